// Round 6
// baseline (88.874 us; speedup 1.0000x reference)
//
#include <hip/hip_runtime.h>
#include <stdint.h>
#include <stddef.h>

// AdderNet 2D: out[n,f,i,j] = -sum_{c,kh,kw} |xpad[n,c,i+kh,j+kw] - W[f,c,kh,kw]|
// x: [16,32,56,56] f32, W: [64,32,3,3] f32, out: [16,64,56,56] f32. PAD=1, STRIDE=1.
//
// R6: w moved from the scalar pipe (SQC-miss serialized, out-of-order lgkmcnt(0)
// drains) into LDS. Block = 4 waves (4 consecutive rows) x ONE filter-group of 8;
// block stages its fg's 32ch x 72 w-floats (9.2 KB) to LDS once, then each channel
// does 18 broadcast ds_read_b128 -> 72 VGPRs (DS is in-order -> counted waits
// pipeline). x via per-row buffer SRDs: HW OOB-zero == zero-pad semantics.

#define N_   16
#define C_   32
#define H_   56
#define F_   64
#define HW_  3136
#define FPW  8
#define NFG  8
#define ROWB 224
#define TPB  256

typedef int   int32x4 __attribute__((ext_vector_type(4)));
typedef float f32x4   __attribute__((ext_vector_type(4)));

__device__ float __buf_load_f32(int32x4 srsrc, int voffset, int soffset, int aux) __asm("llvm.amdgcn.raw.buffer.load.f32");

__device__ inline int32x4 make_srd(const void* p, int bytes) {
    union { const void* p; uint32_t u[2]; } a; a.p = p;
    int32x4 r;
    r.x = (int)a.u[0];
    r.y = (int)a.u[1];        // VA < 2^48, high bits 0 -> stride field 0
    r.z = bytes;              // num_records (stride==0 -> bytes)
    r.w = 0x00020000;         // raw untyped dword
    return r;
}

__global__ __launch_bounds__(TPB, 4)
void adder_main(const float* __restrict__ x,
                const float* __restrict__ w,
                float* __restrict__ out) {
    __shared__ f32x4 lds_w[C_ * 18];   // [c][18 x float4] = 72 floats/channel, 9216 B

    const int tid  = threadIdx.x;
    const int lane = tid & 63;
    const int wid  = tid >> 6;          // 0..3 -> row within the block's row group
    const int bid  = blockIdx.x;
    const int fg   = bid & (NFG - 1);
    const int bid2 = bid >> 3;
    const int rg   = bid2 % 14;         // 14 row groups of 4
    const int n    = bid2 / 14;
    const int f0   = fg * FPW;

    // ---- stage this fg's weights: lds[c*72 + fi*9 + kk] = W[(f0+fi)*288 + c*9 + kk]
    {
        float* l = (float*)lds_w;
        for (int e = tid; e < C_ * 72; e += TPB) {
            int c  = e / 72;
            int rr = e % 72;
            int fi = rr / 9;
            int kk = rr % 9;
            l[e] = w[((f0 + fi) * C_ + c) * 9 + kk];
        }
    }
    __syncthreads();

    // wave's output row; force scalar so the x SRDs stay in SGPRs (R4 lesson)
    const int row = __builtin_amdgcn_readfirstlane(rg * 4 + wid);

    const int vA = (lane - 1) * 4;   // col j-1 (lane 0 -> 0xFFFFFFFC -> HW OOB zero)
    const int vB = lane * 4;         // col j   (+soffset 4 -> col j+1)

    const int nr0 = (row >= 1)      ? ROWB : 0;   // kh=0 row validity
    const int nr2 = (row <= H_ - 2) ? ROWB : 0;   // kh=2

    const float* xb = x + (size_t)n * C_ * HW_ + (ptrdiff_t)(row - 1) * H_;

    float acc[FPW];
#pragma unroll
    for (int f = 0; f < FPW; ++f) acc[f] = 0.0f;

    float xva[9], xvb[9];
    f32x4 warr[18];

    auto load_ch = [&](int c, float* v) {
        const float* b = xb + (size_t)c * HW_;
        int32x4 s0 = make_srd(b,          nr0);
        int32x4 s1 = make_srd(b + H_,     ROWB);
        int32x4 s2 = make_srd(b + 2 * H_, nr2);
        v[0] = __buf_load_f32(s0, vA, 0, 0);
        v[1] = __buf_load_f32(s0, vB, 0, 0);
        v[2] = __buf_load_f32(s0, vB, 4, 0);
        v[3] = __buf_load_f32(s1, vA, 0, 0);
        v[4] = __buf_load_f32(s1, vB, 0, 0);
        v[5] = __buf_load_f32(s1, vB, 4, 0);
        v[6] = __buf_load_f32(s2, vA, 0, 0);
        v[7] = __buf_load_f32(s2, vB, 0, 0);
        v[8] = __buf_load_f32(s2, vB, 4, 0);
    };

    auto compute = [&](int c, const float* cur) {
        // 18 broadcast ds_read_b128 -> 72 VGPRs (in-order, counted lgkm waits)
#pragma unroll
        for (int j = 0; j < 18; ++j) warr[j] = lds_w[c * 18 + j];
#pragma unroll
        for (int f = 0; f < FPW; ++f) {
#pragma unroll
            for (int k = 0; k < 9; ++k) {
                const int i = f * 9 + k;
                acc[f] += fabsf(cur[k] - warr[i >> 2][i & 3]);
            }
        }
    };

    load_ch(0, xva);
    for (int c = 0; c < C_; c += 2) {
        load_ch(c + 1, xvb);          // c+1 <= 31 always (C_ even)
        compute(c, xva);
        if (c + 2 < C_) load_ch(c + 2, xva);
        compute(c + 1, xvb);
    }

    if (lane < H_) {
#pragma unroll
        for (int f = 0; f < FPW; ++f)
            out[(size_t)(n * F_ + f0 + f) * HW_ + row * H_ + lane] = -acc[f];
    }
}

extern "C" void kernel_launch(void* const* d_in, const int* in_sizes, int n_in,
                              void* d_out, int out_size, void* d_ws, size_t ws_size,
                              hipStream_t stream) {
    const float* x = (const float*)d_in[0];
    const float* w = (const float*)d_in[1];
    float* out = (float*)d_out;
    adder_main<<<dim3(N_ * 14 * NFG), dim3(TPB), 0, stream>>>(x, w, out);
}